// Round 11
// baseline (4777.297 us; speedup 1.0000x reference)
//
#include <hip/hip_runtime.h>

// WholeBrainFastDMF: N=360, B=8, T=7500 neural steps (750 hemo).
// One persistent block (1 CU) per batch, 8 waves / 512 threads.
// HETEROGENEOUS WAVE CLASSES (pipe overlap per m114):
//   waves 0-3 (m-class): rows 0..191 via v_mfma_i32_16x16x64_i8 (3 tiles/wave,
//     E broadcast across B-columns -> conn lands in own acc regs, R8 machinery).
//   waves 4-7 (d-class): rows 192..359 via VALU sdot4 (42 rows/wave, quad
//     layout: lane=4*rg+cg, 3 rows x 96-col chunk each, DPP butterfly, R5
//     machinery).
// Each SIMD hosts one wave of each class -> d-wave VALU dot issue overlaps
// m-wave MFMA pipe time. Both paths are exact int8 dot products -> conn is
// bit-identical to the R8 kernel (absmax must stay exactly 0.03125).
// E int8 double-buffered in LDS (linear 384B, zero pad 360..383).
// One lgkm-only barrier per step; 2-step noise prefetch; fast rcp/exp2/log2.

typedef unsigned int u32;
typedef int i32x4 __attribute__((ext_vector_type(4)));

#define NN 360
#define NB 8
#define NT 7500
#define NHEMO 750

#define S_SC 45720.0f            // sc scale: sc*360 in [0,1) -> *127
#define S_E  64.0f               // E scale (E < 1.98)
#define CONN_K 1.0252653e-7f     // 0.3 / (45720*64)   (G*JN = 0.3 folded)

#if __has_builtin(__builtin_amdgcn_sdot4)
#define DOT4(a,b,c) __builtin_amdgcn_sdot4((a),(b),(c),false)
#elif __has_builtin(__builtin_amdgcn_udot4)
#define DOT4(a,b,c) (int)__builtin_amdgcn_udot4((u32)(a),(u32)(b),(u32)(c),false)
#else
static __device__ __forceinline__ int DOT4(int a, int b, int c) {
  #pragma unroll
  for (int i = 0; i < 4; ++i) c += ((a >> (8*i)) & 0xff) * ((b >> (8*i)) & 0xff);
  return c;
}
#endif

__device__ __forceinline__ float frcp(float x) {
#if __has_builtin(__builtin_amdgcn_rcpf)
  return __builtin_amdgcn_rcpf(x);
#else
  return 1.0f / x;
#endif
}
__device__ __forceinline__ float fexp2(float x) {
#if __has_builtin(__builtin_amdgcn_exp2f)
  return __builtin_amdgcn_exp2f(x);
#else
  return exp2f(x);
#endif
}
__device__ __forceinline__ float flog2(float x) {
#if __has_builtin(__builtin_amdgcn_logf)
  return __builtin_amdgcn_logf(x);
#else
  return log2f(x);
#endif
}

template <int CTRL>
__device__ __forceinline__ int dpp_add_i(int x) {
  return x + __builtin_amdgcn_mov_dpp(x, CTRL, 0xF, 0xF, true);
}
template <int CTRL>
__device__ __forceinline__ float dpp_add_f(float x) {
  return x + __int_as_float(__builtin_amdgcn_mov_dpp(__float_as_int(x), CTRL, 0xF, 0xF, true));
}
// quad_perm xor1 = 0xB1, xor2 = 0x4E

// Workgroup barrier with lgkm-only drain: ds_write made visible, VMEM
// prefetches stay in flight across the barrier. (R8's exact version.)
__device__ __forceinline__ void lds_barrier() {
  __builtin_amdgcn_sched_barrier(0);
  asm volatile("s_waitcnt lgkmcnt(0)" ::: "memory");
  __builtin_amdgcn_s_barrier();
  asm volatile("" ::: "memory");
  __builtin_amdgcn_sched_barrier(0);
}

__global__ __launch_bounds__(512, 2) void dmf_kernel(
    const float* __restrict__ state,
    const float* __restrict__ noise_in,
    const float* __restrict__ noise_out,
    const float* __restrict__ sc,
    float* __restrict__ out)
{
  const int b   = blockIdx.x;
  const int tid = threadIdx.x;
  const int w   = tid >> 6;
  const int l   = tid & 63;
  const bool mcl = (w < 4);      // wave class: MFMA (rows 0..191) vs dot (192..359)

  // m-class decode
  const int g   = l >> 4;        // k-slice group / C row-group
  const int r   = l & 15;        // A row within tile / C col
  const int t_o = r >> 2;        // owner tile (valid < 3)
  const int j_o = r & 3;         // acc register index
  // d-class decode
  const int cg  = l & 3;         // column chunk (96 cols) AND in-quad row index
  const int rg  = l >> 2;        // row group (3 rows), 0..15 (valid < 14)

  int R_o; bool upd;
  if (mcl) {
    R_o = 48*w + 16*t_o + 4*g + j_o;           // 0..191
    upd = (r < 12);
  } else {
    R_o = 192 + 42*(w - 4) + 3*rg + cg;        // 192..359
    upd = (cg < 3) && (rg < 14);
  }
  const int Rn = upd ? R_o : 0;

  __shared__ u32 xq[2][96];      // int8 E, linear 384B each (360 data + 24 zero)

  if (tid < 192) ((u32*)xq)[tid] = 0;   // zero both buffers (pads stay 0)

  // ---- per-class sc quantize + row sums ----
  i32x4 afr[3][6];               // m-class A-frags (72 VGPRs)
  int   scp[3][24];              // d-class packed rows (72 VGPRs)
  float rsum = 0.f;

  if (mcl) {
    float rs[3];
    #pragma unroll
    for (int t = 0; t < 3; ++t) {
      const int R = 48*w + 16*t + r;           // always < 192: valid
      const float* sp = sc + ((size_t)b*NN + R)*NN;
      float acc = 0.f;
      #pragma unroll
      for (int kf = 0; kf < 6; ++kf) {
        i32x4 pk;
        #pragma unroll
        for (int d = 0; d < 4; ++d) {
          int packv = 0;
          #pragma unroll
          for (int e = 0; e < 4; ++e) {
            const int k = 64*kf + 16*g + 4*d + e;
            int q = 0;
            if (k < NN) {
              const float x = sp[k];
              acc += x;
              q = (int)rintf(x * S_SC);
            }
            packv |= q << (8*e);
          }
          pk[d] = packv;
        }
        afr[t][kf] = pk;
      }
      rs[t] = acc;
    }
    #pragma unroll
    for (int t = 0; t < 3; ++t) {
      rs[t] += __shfl_xor(rs[t], 16, 64);
      rs[t] += __shfl_xor(rs[t], 32, 64);
    }
    const int rho = 4*g + j_o;
    const int qs0 = __builtin_amdgcn_ds_bpermute(4*rho, __float_as_int(rs[0]));
    const int qs1 = __builtin_amdgcn_ds_bpermute(4*rho, __float_as_int(rs[1]));
    const int qs2 = __builtin_amdgcn_ds_bpermute(4*rho, __float_as_int(rs[2]));
    rsum = __int_as_float((t_o == 0) ? qs0 : ((t_o == 1) ? qs1 : qs2));
  } else {
    float rs[3];
    const int base = 192 + 42*(w - 4);
    #pragma unroll
    for (int j = 0; j < 3; ++j) {
      const int rr = 3*rg + j;                 // row slot (valid < 42)
      const bool rv = (rr < 42);
      const float* sp = sc + ((size_t)b*NN + (rv ? base + rr : 0))*NN;
      float rsj = 0.f;
      #pragma unroll
      for (int k = 0; k < 24; ++k) {
        int packv = 0;
        #pragma unroll
        for (int e = 0; e < 4; ++e) {
          const int cc = 96*cg + 4*k + e;
          int q = 0;
          if (rv && cc < NN) {
            const float x = sp[cc];
            rsj += x;
            q = (int)rintf(x * S_SC);
          }
          packv |= q << (8*e);
        }
        scp[j][k] = packv;
      }
      rs[j] = rsj;
    }
    #pragma unroll
    for (int j = 0; j < 3; ++j) {
      rs[j] = dpp_add_f<0xB1>(rs[j]);
      rs[j] = dpp_add_f<0x4E>(rs[j]);
    }
    rsum = (cg == 0) ? rs[0] : ((cg == 1) ? rs[1] : rs[2]);
  }

  // ---- owner init: Ji, state, publish E into buffer 0, noise t=0,1 ----
  float E=0.f, I=0.f, ss=0.f, ff=0.f, vv=0.f, qq=0.f, Ji=0.f;
  const float* np = noise_in + (size_t)Rn * NT * 2 * NB + b;
  float n0E=0.f, n0I=0.f, n1E=0.f, n1I=0.f;
  __syncthreads();   // xq zeroing complete
  if (upd) {
    Ji = 1.0f + 1.5f * rsum;
    const float* st = state + (size_t)R_o * 6 * NB + b;
    E  = st[0];
    I  = st[NB];
    ss = st[2*NB];
    ff = st[3*NB];
    vv = st[4*NB];
    qq = st[5*NB];
    int qv = (int)rintf(E * S_E);
    qv = qv > 127 ? 127 : qv;
    ((char*)&xq[0][0])[R_o] = (char)qv;
    n0E = np[0];      n0I = np[NB];       // t = 0
    n1E = np[2*NB];   n1I = np[3*NB];     // t = 1
  }
  np += 4*NB;        // points at t = 2
  __syncthreads();   // buffer 0 visible

  // per-lane read base: m-class strides 64B (frag kf at +16kf dwords),
  // d-class contiguous 96B chunk (frag kk at +4kk dwords)
  const u32* rb0 = &xq[0][0] + (mcl ? 4*g : 24*cg);
  const u32* rb1 = &xq[1][0] + (mcl ? 4*g : 24*cg);
  char* pb0 = (char*)&xq[0][0] + Rn;
  char* pb1 = (char*)&xq[1][0] + Rn;

  // one neural step: read E-frags from rb, write E byte at pbn
  auto body = [&](const u32* rb, char* pbn, bool PF, bool hemo) {
    // noise prefetch t+2 (stays in flight across lgkm-only barriers)
    float n2E = n1E, n2I = n1I;
    if (PF) {
      if (upd) { n2E = np[0]; n2I = np[NB]; }
      np += 2*NB;
    }

    int ci;
    if (mcl) {
      // ---- MFMA path: 3 tiles x 6 k-frags ----
      i32x4 bf[6];
      #pragma unroll
      for (int kf = 0; kf < 6; ++kf) bf[kf] = *(const i32x4*)(rb + 16*kf);
      i32x4 ac0 = {0,0,0,0}, ac1 = {0,0,0,0}, ac2 = {0,0,0,0};
      #pragma unroll
      for (int kf = 0; kf < 6; ++kf)
        ac0 = __builtin_amdgcn_mfma_i32_16x16x64_i8(afr[0][kf], bf[kf], ac0, 0, 0, 0);
      #pragma unroll
      for (int kf = 0; kf < 6; ++kf)
        ac1 = __builtin_amdgcn_mfma_i32_16x16x64_i8(afr[1][kf], bf[kf], ac1, 0, 0, 0);
      #pragma unroll
      for (int kf = 0; kf < 6; ++kf)
        ac2 = __builtin_amdgcn_mfma_i32_16x16x64_i8(afr[2][kf], bf[kf], ac2, 0, 0, 0);
      const i32x4 at = (t_o == 0) ? ac0 : ((t_o == 1) ? ac1 : ac2);
      ci = (j_o == 0) ? at.x : ((j_o == 1) ? at.y : ((j_o == 2) ? at.z : at.w));
    } else {
      // ---- dot4 path: 3 rows x 96 cols, quad butterfly ----
      i32x4 ev4[6];
      #pragma unroll
      for (int kk = 0; kk < 6; ++kk) ev4[kk] = *(const i32x4*)(rb + 4*kk);
      int a0 = 0, a1 = 0, a2 = 0;
      #pragma unroll
      for (int kk = 0; kk < 6; ++kk) {
        #pragma unroll
        for (int d = 0; d < 4; ++d) {
          const int ex = ev4[kk][d];
          a0 = DOT4(scp[0][4*kk + d], ex, a0);
          a1 = DOT4(scp[1][4*kk + d], ex, a1);
          a2 = DOT4(scp[2][4*kk + d], ex, a2);
        }
      }
      a0 = dpp_add_i<0xB1>(a0); a0 = dpp_add_i<0x4E>(a0);
      a1 = dpp_add_i<0xB1>(a1); a1 = dpp_add_i<0x4E>(a1);
      a2 = dpp_add_i<0xB1>(a2); a2 = dpp_add_i<0x4E>(a2);
      ci = (cg == 0) ? a0 : ((cg == 1) ? a1 : a2);
    }

    if (upd) {
      const float cs = (float)ci * CONN_K;                 // G*JN*conn
      float I_E = fmaxf(0.382f + 0.21f*E + cs - Ji*I, 0.f);
      float I_I = fmaxf(0.2674f + 0.15f*E - I, 0.f);
      const float xE  = 310.f*I_E - 125.f;
      const float R_E = xE * frcp(1.f - fexp2(-0.23083120f*xE) + 1e-8f);
      const float xI  = 615.f*I_I - 177.f;
      const float R_I = xI * frcp(1.f - fexp2(-0.12551447f*xI) + 1e-8f);
      const float dE = -E*0.01f + (1.f - E)*0.000641f*R_E;
      const float dI = -I*0.1f  + 0.001f*R_I;
      E = fmaxf(E + 0.1f*dE + 0.00158113883f*n0E, 0.f);
      I = fmaxf(I + 0.1f*dI + 0.00158113883f*n0I, 0.f);
      int qv = (int)(E * S_E + 0.5f);
      qv = qv > 127 ? 127 : qv;
      *pbn = (char)qv;
      if (hemo) {
        const float l2v  = flog2(vv);
        const float v_ia = fexp2(3.125f * l2v);            // v**(1/0.32)
        const float v_r  = fexp2(2.125f * l2v);            // v**(1/0.32-1)
        const float ds_  = E - 1.53846153846f*ss - 2.43902439024f*(ff - 1.f);
        const float df_  = ss;
        const float dv_  = (ff - v_ia) * 1.02040816327f;
        const float pw   = fexp2(-0.59946207f * frcp(ff)); // (1-RHO)**(1/f)
        const float dq_  = (ff*2.94117647059f*(1.f - pw) - qq*v_r) * 1.02040816327f;
        ss += 1e-3f*ds_;
        ff += 1e-3f*df_;
        vv += 1e-3f*dv_;
        qq += 1e-3f*dq_;
      }
    }
    n0E = n1E; n0I = n1I;
    n1E = n2E; n1I = n2I;
    lds_barrier();   // next buffer complete; vmcnt loads stay in flight
  };

  for (int hs = 0; hs < NHEMO; ++hs) {
    body(rb0, pb1, true, false);
    body(rb1, pb0, true, false);
    body(rb0, pb1, true, false);
    body(rb1, pb0, true, false);
    body(rb0, pb1, true, false);
    body(rb1, pb0, true, false);
    body(rb0, pb1, true, false);
    body(rb1, pb0, true, false);
    if (hs != NHEMO - 1) {
      body(rb0, pb1, true, false);
      body(rb1, pb0, true, true);
    } else {
      body(rb0, pb1, false, false);
      body(rb1, pb0, false, true);
    }
  }

  // ---- outputs: next_state (N,6,B) then bold (N,B) ----
  if (upd) {
    float* o = out + (size_t)R_o * 6 * NB + b;
    o[0]    = E;
    o[NB]   = I;
    o[2*NB] = ss;
    o[3*NB] = ff;
    o[4*NB] = vv;
    o[5*NB] = qq;
    out[NN*6*NB + R_o*NB + b] =
        20.f*(2.38f*(1.f - qq) + 2.f*(1.f - qq/vv) + 0.48f*(1.f - vv))
        + noise_out[R_o*NB + b];
  }
}

extern "C" void kernel_launch(void* const* d_in, const int* in_sizes, int n_in,
                              void* d_out, int out_size, void* d_ws, size_t ws_size,
                              hipStream_t stream) {
  const float* state     = (const float*)d_in[0];
  // d_in[1] = delays (unused by the reference simulation)
  const float* noise_in  = (const float*)d_in[2];
  const float* noise_out = (const float*)d_in[3];
  const float* sc        = (const float*)d_in[4];
  float* out = (float*)d_out;
  dmf_kernel<<<NB, 512, 0, stream>>>(state, noise_in, noise_out, sc, out);
}

// Round 12
// 4578.147 us; speedup vs baseline: 1.0435x; 1.0435x over previous
//
#include <hip/hip_runtime.h>

// WholeBrainFastDMF: N=360, B=8, T=7500 neural steps (750 hemo).
// One persistent block (1 CU) per batch, 8 waves / 512 threads.
// Matvec on the MFMA pipe (v_mfma_i32_16x16x64_i8), E broadcast across all 16
// B-columns -> lane (g<<4|c) holds y[16T+4g+reg] in its own acc regs, zero
// shuffle extraction. Wave w owns rows [48w,48w+48) as 3 row-tiles of 16.
// R12 (on the R8 base = 4388us): EARLY BARRIER. Only E crosses the barrier;
// the I-update, hemo step and noise-register rotations are wave-private, so
// they run AFTER s_barrier, overlapping the next step's ds_read/MFMA window.
// Per-step critical chain loses the I-chain (~15 serial ops incl exp2+rcp).
// Float math unchanged & identically ordered -> absmax must stay 0.03125.

typedef unsigned int u32;
typedef int i32x4 __attribute__((ext_vector_type(4)));

#define NN 360
#define NB 8
#define NT 7500
#define NHEMO 750

#define S_SC 45720.0f            // sc scale: sc*360 in [0,1) -> *127
#define S_E  64.0f               // E scale (E < 1.98)
#define CONN_K 1.0252653e-7f     // 0.3 / (45720*64)   (G*JN = 0.3 folded)

__device__ __forceinline__ float frcp(float x) {
#if __has_builtin(__builtin_amdgcn_rcpf)
  return __builtin_amdgcn_rcpf(x);
#else
  return 1.0f / x;
#endif
}
__device__ __forceinline__ float fexp2(float x) {
#if __has_builtin(__builtin_amdgcn_exp2f)
  return __builtin_amdgcn_exp2f(x);
#else
  return exp2f(x);
#endif
}
__device__ __forceinline__ float flog2(float x) {
#if __has_builtin(__builtin_amdgcn_logf)
  return __builtin_amdgcn_logf(x);
#else
  return log2f(x);
#endif
}

// Workgroup barrier with lgkm-only drain: ds_write made visible, VMEM
// prefetches stay in flight across the barrier. Trailing sched fence pins
// post-barrier work (I-path) below the barrier and next-step ds_reads too.
__device__ __forceinline__ void lds_barrier() {
  __builtin_amdgcn_sched_barrier(0);
  asm volatile("s_waitcnt lgkmcnt(0)" ::: "memory");
  __builtin_amdgcn_s_barrier();
  asm volatile("" ::: "memory");
  __builtin_amdgcn_sched_barrier(0);
}

__global__ __launch_bounds__(512, 2) void dmf_kernel(
    const float* __restrict__ state,
    const float* __restrict__ noise_in,
    const float* __restrict__ noise_out,
    const float* __restrict__ sc,
    float* __restrict__ out)
{
  const int b   = blockIdx.x;
  const int tid = threadIdx.x;
  const int w   = tid >> 6;
  const int l   = tid & 63;
  const int g   = l >> 4;        // k-slice group (A/B) AND C row-group
  const int r   = l & 15;        // A row within tile; also C col index c
  // owner decode: lane (g<<4)|c with c<12 owns row 48w + 16*(c>>2) + 4g + (c&3)
  const int t_o = r >> 2;        // owner tile 0..3 (valid < 3)
  const int j_o = r & 3;         // acc register index
  const int R_o = 48*w + 16*t_o + 4*g + j_o;
  const bool upd = (r < 12) && (R_o < NN);
  const int Rn  = upd ? R_o : 0; // safe row for address bases

  __shared__ u32 xq[2][96];      // int8 E, linear 384B each (360 data + 24 zero)

  if (tid < 192) ((u32*)xq)[tid] = 0;   // zero both buffers (pads stay 0)

  // ---- build A-frags: quantize sc rows into MFMA layout; f32 row sums ----
  i32x4 afr[3][6];
  float rs[3];
  #pragma unroll
  for (int t = 0; t < 3; ++t) {
    const int R = 48*w + 16*t + r;
    const bool rv = (R < NN);
    const float* sp = sc + ((size_t)b*NN + (rv ? R : 0))*NN;
    float acc = 0.f;
    #pragma unroll
    for (int kf = 0; kf < 6; ++kf) {
      i32x4 pk;
      #pragma unroll
      for (int d = 0; d < 4; ++d) {
        int packv = 0;
        #pragma unroll
        for (int e = 0; e < 4; ++e) {
          const int k = 64*kf + 16*g + 4*d + e;
          int q = 0;
          if (rv && k < NN) {
            const float x = sp[k];
            acc += x;
            q = (int)rintf(x * S_SC);
          }
          packv |= q << (8*e);
        }
        pk[d] = packv;
      }
      afr[t][kf] = pk;
    }
    rs[t] = acc;
  }
  // full row sums: reduce over the 4 k-slice groups (lanes ^16, ^32)
  #pragma unroll
  for (int t = 0; t < 3; ++t) {
    rs[t] += __shfl_xor(rs[t], 16, 64);
    rs[t] += __shfl_xor(rs[t], 32, 64);
  }
  // owner pulls rowsum of in-tile row rho = 4g + j_o (held by lane rho, tile t_o)
  const int rho = 4*g + j_o;
  const int qs0 = __builtin_amdgcn_ds_bpermute(4*rho, __float_as_int(rs[0]));
  const int qs1 = __builtin_amdgcn_ds_bpermute(4*rho, __float_as_int(rs[1]));
  const int qs2 = __builtin_amdgcn_ds_bpermute(4*rho, __float_as_int(rs[2]));
  const float rsum = __int_as_float((t_o == 0) ? qs0 : ((t_o == 1) ? qs1 : qs2));

  // ---- owner init: Ji, state, publish E into buffer 0, noise t=0,1 ----
  float E=0.f, I=0.f, ss=0.f, ff=0.f, vv=0.f, qq=0.f, Ji=0.f;
  const float* np = noise_in + (size_t)Rn * NT * 2 * NB + b;
  float n0E=0.f, n0I=0.f, n1E=0.f, n1I=0.f;
  __syncthreads();   // xq zeroing complete
  if (upd) {
    Ji = 1.0f + 1.5f * rsum;
    const float* st = state + (size_t)R_o * 6 * NB + b;
    E  = st[0];
    I  = st[NB];
    ss = st[2*NB];
    ff = st[3*NB];
    vv = st[4*NB];
    qq = st[5*NB];
    int qv = (int)rintf(E * S_E);
    qv = qv > 127 ? 127 : qv;
    ((char*)&xq[0][0])[R_o] = (char)qv;
    n0E = np[0];      n0I = np[NB];       // t = 0
    n1E = np[2*NB];   n1I = np[3*NB];     // t = 1
  }
  np += 4*NB;        // points at t = 2
  __syncthreads();   // buffer 0 visible

  const u32* xb0 = &xq[0][4*g];
  const u32* xb1 = &xq[1][4*g];
  char* pb0 = (char*)&xq[0][0] + Rn;
  char* pb1 = (char*)&xq[1][0] + Rn;
  const bool w7 = (w == 7);      // wave 7 tile 2 = rows 368..383, all zero

  // one neural step: read B-frags from xb, write E byte at pbn.
  // PRE-barrier: matvec + E-path (E' is all other waves need).
  // POST-barrier: I-path + hemo + noise rotations (wave-private, overlap
  // the next step's ds_read/MFMA window).
  auto body = [&](const u32* xb, char* pbn, bool PF, bool hemo) {
    // 1) B-frags (6 x ds_read_b128, broadcast within each 16-lane group)
    i32x4 bf[6];
    #pragma unroll
    for (int kf = 0; kf < 6; ++kf) bf[kf] = *(const i32x4*)(xb + 16*kf);

    // 2) noise prefetch t+2 (stays in flight across lgkm-only barriers)
    float n2E = n1E, n2I = n1I;
    if (PF) {
      if (upd) { n2E = np[0]; n2I = np[NB]; }
      np += 2*NB;
    }

    // 3) matvec on the MFMA pipe: 3 accumulate chains of 6 (R8 structure)
    i32x4 ac0 = {0,0,0,0}, ac1 = {0,0,0,0}, ac2 = {0,0,0,0};
    #pragma unroll
    for (int kf = 0; kf < 6; ++kf)
      ac0 = __builtin_amdgcn_mfma_i32_16x16x64_i8(afr[0][kf], bf[kf], ac0, 0, 0, 0);
    #pragma unroll
    for (int kf = 0; kf < 6; ++kf)
      ac1 = __builtin_amdgcn_mfma_i32_16x16x64_i8(afr[1][kf], bf[kf], ac1, 0, 0, 0);
    if (!w7) {
      #pragma unroll
      for (int kf = 0; kf < 6; ++kf)
        ac2 = __builtin_amdgcn_mfma_i32_16x16x64_i8(afr[2][kf], bf[kf], ac2, 0, 0, 0);
    }

    // 4) conn: every B-column equals y, so acc reg j_o of tile t_o IS y[R_o]
    const i32x4 at = (t_o == 0) ? ac0 : ((t_o == 1) ? ac1 : ac2);
    const int ci = (j_o == 0) ? at.x : ((j_o == 1) ? at.y : ((j_o == 2) ? at.z : at.w));

    // 5) E-path only (critical): E' -> quantize -> ds_write
    const float Eold = E;
    if (upd) {
      const float cs = (float)ci * CONN_K;                 // G*JN*conn
      float I_E = fmaxf(0.382f + 0.21f*Eold + cs - Ji*I, 0.f);
      const float xE  = 310.f*I_E - 125.f;
      const float R_E = xE * frcp(1.f - fexp2(-0.23083120f*xE) + 1e-8f);
      const float dE = -Eold*0.01f + (1.f - Eold)*0.000641f*R_E;
      E = fmaxf(Eold + 0.1f*dE + 0.00158113883f*n0E, 0.f);
      int qv = (int)(E * S_E + 0.5f);
      qv = qv > 127 ? 127 : qv;
      *pbn = (char)qv;
    }

    lds_barrier();   // E visible; vmcnt loads stay in flight

    // 6) I-path + hemo: wave-private, overlaps next step's ds_read/MFMA
    if (upd) {
      float I_I = fmaxf(0.2674f + 0.15f*Eold - I, 0.f);
      const float xI  = 615.f*I_I - 177.f;
      const float R_I = xI * frcp(1.f - fexp2(-0.12551447f*xI) + 1e-8f);
      const float dI = -I*0.1f  + 0.001f*R_I;
      I = fmaxf(I + 0.1f*dI + 0.00158113883f*n0I, 0.f);
      if (hemo) {
        const float l2v  = flog2(vv);
        const float v_ia = fexp2(3.125f * l2v);            // v**(1/0.32)
        const float v_r  = fexp2(2.125f * l2v);            // v**(1/0.32-1)
        const float ds_  = E - 1.53846153846f*ss - 2.43902439024f*(ff - 1.f);
        const float df_  = ss;
        const float dv_  = (ff - v_ia) * 1.02040816327f;
        const float pw   = fexp2(-0.59946207f * frcp(ff)); // (1-RHO)**(1/f)
        const float dq_  = (ff*2.94117647059f*(1.f - pw) - qq*v_r) * 1.02040816327f;
        ss += 1e-3f*ds_;
        ff += 1e-3f*df_;
        vv += 1e-3f*dv_;
        qq += 1e-3f*dq_;
      }
    }
    n0E = n1E; n0I = n1I;
    n1E = n2E; n1I = n2I;
  };

  for (int hs = 0; hs < NHEMO; ++hs) {
    body(xb0, pb1, true, false);
    body(xb1, pb0, true, false);
    body(xb0, pb1, true, false);
    body(xb1, pb0, true, false);
    body(xb0, pb1, true, false);
    body(xb1, pb0, true, false);
    body(xb0, pb1, true, false);
    body(xb1, pb0, true, false);
    if (hs != NHEMO - 1) {
      body(xb0, pb1, true, false);
      body(xb1, pb0, true, true);
    } else {
      body(xb0, pb1, false, false);
      body(xb1, pb0, false, true);
    }
  }

  // ---- outputs: next_state (N,6,B) then bold (N,B) ----
  if (upd) {
    float* o = out + (size_t)R_o * 6 * NB + b;
    o[0]    = E;
    o[NB]   = I;
    o[2*NB] = ss;
    o[3*NB] = ff;
    o[4*NB] = vv;
    o[5*NB] = qq;
    out[NN*6*NB + R_o*NB + b] =
        20.f*(2.38f*(1.f - qq) + 2.f*(1.f - qq/vv) + 0.48f*(1.f - vv))
        + noise_out[R_o*NB + b];
  }
}

extern "C" void kernel_launch(void* const* d_in, const int* in_sizes, int n_in,
                              void* d_out, int out_size, void* d_ws, size_t ws_size,
                              hipStream_t stream) {
  const float* state     = (const float*)d_in[0];
  // d_in[1] = delays (unused by the reference simulation)
  const float* noise_in  = (const float*)d_in[2];
  const float* noise_out = (const float*)d_in[3];
  const float* sc        = (const float*)d_in[4];
  float* out = (float*)d_out;
  dmf_kernel<<<NB, 512, 0, stream>>>(state, noise_in, noise_out, sc, out);
}

// Round 13
// 4386.977 us; speedup vs baseline: 1.0890x; 1.0436x over previous
//
#include <hip/hip_runtime.h>

// WholeBrainFastDMF: N=360, B=8, T=7500 neural steps (750 hemo).
// One persistent block (1 CU) per batch, 8 waves / 512 threads.
// MATVEC ON THE MFMA PIPE: conn = sc_q(int8) . E_q(int8) via
// v_mfma_i32_16x16x64_i8, with E broadcast across all 16 B-columns so every
// column of C equals y -> lane (g<<4|c) holds y[16T+4g+reg] in its own acc
// regs (C layout: col=lane&15, row=(lane>>4)*4+reg). No butterfly, no
// handoff. Wave w owns rows [48w,48w+48) as 3 row-tiles of 16.
// A-frags: 3 tiles x 6 kfrags x 4 VGPRs = 72 (int8, k-slices per lane-group).
// E int8 double-buffered in LDS (linear 384B, zero pad 360..383).
// One lgkm-only barrier per step; 2-step noise prefetch; fast rcp/exp2/log2.
// [This is the round-8 kernel verbatim - best measured at 4388 us. Rounds
// 9-12 probed chain-split/TLP/pipe-split/early-barrier: all neutral or
// negative; reverting to the measured optimum.]

typedef unsigned int u32;
typedef int i32x4 __attribute__((ext_vector_type(4)));

#define NN 360
#define NB 8
#define NT 7500
#define NHEMO 750

#define S_SC 45720.0f            // sc scale: sc*360 in [0,1) -> *127
#define S_E  64.0f               // E scale (E < 1.98)
#define CONN_K 1.0252653e-7f     // 0.3 / (45720*64)   (G*JN = 0.3 folded)

__device__ __forceinline__ float frcp(float x) {
#if __has_builtin(__builtin_amdgcn_rcpf)
  return __builtin_amdgcn_rcpf(x);
#else
  return 1.0f / x;
#endif
}
__device__ __forceinline__ float fexp2(float x) {
#if __has_builtin(__builtin_amdgcn_exp2f)
  return __builtin_amdgcn_exp2f(x);
#else
  return exp2f(x);
#endif
}
__device__ __forceinline__ float flog2(float x) {
#if __has_builtin(__builtin_amdgcn_logf)
  return __builtin_amdgcn_logf(x);
#else
  return log2f(x);
#endif
}

// Workgroup barrier WITHOUT vmcnt drain (LDS-visibility only).
__device__ __forceinline__ void lds_barrier() {
  __builtin_amdgcn_sched_barrier(0);
  asm volatile("s_waitcnt lgkmcnt(0)" ::: "memory");
  __builtin_amdgcn_s_barrier();
  asm volatile("" ::: "memory");
  __builtin_amdgcn_sched_barrier(0);
}

__global__ __launch_bounds__(512, 2) void dmf_kernel(
    const float* __restrict__ state,
    const float* __restrict__ noise_in,
    const float* __restrict__ noise_out,
    const float* __restrict__ sc,
    float* __restrict__ out)
{
  const int b   = blockIdx.x;
  const int tid = threadIdx.x;
  const int w   = tid >> 6;
  const int l   = tid & 63;
  const int g   = l >> 4;        // k-slice group (A/B) AND C row-group
  const int r   = l & 15;        // A row within tile; also C col index c
  // owner decode: lane (g<<4)|c with c<12 owns row 48w + 16*(c>>2) + 4g + (c&3)
  const int t_o = r >> 2;        // owner tile 0..3 (valid < 3)
  const int j_o = r & 3;         // acc register index
  const int R_o = 48*w + 16*t_o + 4*g + j_o;
  const bool upd = (r < 12) && (R_o < NN);
  const int Rn  = upd ? R_o : 0; // safe row for address bases

  __shared__ u32 xq[2][96];      // int8 E, linear 384B each (360 data + 24 zero)

  if (tid < 192) ((u32*)xq)[tid] = 0;   // zero both buffers (pads stay 0)

  // ---- build A-frags: quantize sc rows into MFMA layout; f32 row sums ----
  // lane supplies row (48w+16t + r), k-bytes 64*kf + 16*g + 0..15
  i32x4 afr[3][6];
  float rs[3];
  #pragma unroll
  for (int t = 0; t < 3; ++t) {
    const int R = 48*w + 16*t + r;
    const bool rv = (R < NN);
    const float* sp = sc + ((size_t)b*NN + (rv ? R : 0))*NN;
    float acc = 0.f;
    #pragma unroll
    for (int kf = 0; kf < 6; ++kf) {
      i32x4 pk;
      #pragma unroll
      for (int d = 0; d < 4; ++d) {
        int packv = 0;
        #pragma unroll
        for (int e = 0; e < 4; ++e) {
          const int k = 64*kf + 16*g + 4*d + e;
          int q = 0;
          if (rv && k < NN) {
            const float x = sp[k];
            acc += x;
            q = (int)rintf(x * S_SC);
          }
          packv |= q << (8*e);
        }
        pk[d] = packv;
      }
      afr[t][kf] = pk;
    }
    rs[t] = acc;
  }
  // full row sums: reduce over the 4 k-slice groups (lanes ^16, ^32)
  #pragma unroll
  for (int t = 0; t < 3; ++t) {
    rs[t] += __shfl_xor(rs[t], 16, 64);
    rs[t] += __shfl_xor(rs[t], 32, 64);
  }
  // owner pulls rowsum of in-tile row rho = 4g + j_o (held by lane rho, tile t_o)
  const int rho = 4*g + j_o;
  const int qs0 = __builtin_amdgcn_ds_bpermute(4*rho, __float_as_int(rs[0]));
  const int qs1 = __builtin_amdgcn_ds_bpermute(4*rho, __float_as_int(rs[1]));
  const int qs2 = __builtin_amdgcn_ds_bpermute(4*rho, __float_as_int(rs[2]));
  const float rsum = __int_as_float((t_o == 0) ? qs0 : ((t_o == 1) ? qs1 : qs2));

  // ---- owner init: Ji, state, publish E into buffer 0, noise t=0,1 ----
  float E=0.f, I=0.f, ss=0.f, ff=0.f, vv=0.f, qq=0.f, Ji=0.f;
  const float* np = noise_in + (size_t)Rn * NT * 2 * NB + b;
  float n0E=0.f, n0I=0.f, n1E=0.f, n1I=0.f;
  __syncthreads();   // xq zeroing complete
  if (upd) {
    Ji = 1.0f + 1.5f * rsum;
    const float* st = state + (size_t)R_o * 6 * NB + b;
    E  = st[0];
    I  = st[NB];
    ss = st[2*NB];
    ff = st[3*NB];
    vv = st[4*NB];
    qq = st[5*NB];
    int qv = (int)rintf(E * S_E);
    qv = qv > 127 ? 127 : qv;
    ((char*)&xq[0][0])[R_o] = (char)qv;
    n0E = np[0];      n0I = np[NB];       // t = 0
    n1E = np[2*NB];   n1I = np[3*NB];     // t = 1
  }
  np += 4*NB;        // points at t = 2
  __syncthreads();   // buffer 0 visible

  const u32* xb0 = &xq[0][4*g];
  const u32* xb1 = &xq[1][4*g];
  char* pb0 = (char*)&xq[0][0] + Rn;
  char* pb1 = (char*)&xq[1][0] + Rn;
  const bool w7 = (w == 7);      // wave 7 tile 2 = rows 368..383, all zero

  // one neural step: read B-frags from xb, write E byte at pbn
  auto body = [&](const u32* xb, char* pbn, bool PF, bool hemo) {
    // 1) B-frags: x k-slice per group g, same for all tiles (6 x ds_read_b128)
    i32x4 bf[6];
    #pragma unroll
    for (int kf = 0; kf < 6; ++kf) bf[kf] = *(const i32x4*)(xb + 16*kf);

    // 2) noise prefetch t+2 (stays in flight across lgkm-only barriers)
    float n2E = n1E, n2I = n1I;
    if (PF) {
      if (upd) { n2E = np[0]; n2I = np[NB]; }
      np += 2*NB;
    }

    // 3) matvec on the MFMA pipe: 3 accumulate chains of 6
    i32x4 ac0 = {0,0,0,0}, ac1 = {0,0,0,0}, ac2 = {0,0,0,0};
    #pragma unroll
    for (int kf = 0; kf < 6; ++kf)
      ac0 = __builtin_amdgcn_mfma_i32_16x16x64_i8(afr[0][kf], bf[kf], ac0, 0, 0, 0);
    #pragma unroll
    for (int kf = 0; kf < 6; ++kf)
      ac1 = __builtin_amdgcn_mfma_i32_16x16x64_i8(afr[1][kf], bf[kf], ac1, 0, 0, 0);
    if (!w7) {
      #pragma unroll
      for (int kf = 0; kf < 6; ++kf)
        ac2 = __builtin_amdgcn_mfma_i32_16x16x64_i8(afr[2][kf], bf[kf], ac2, 0, 0, 0);
    }

    // 4) conn: every B-column equals y, so my acc reg j_o of tile t_o IS y[R_o]
    const i32x4 at = (t_o == 0) ? ac0 : ((t_o == 1) ? ac1 : ac2);
    const int ci = (j_o == 0) ? at.x : ((j_o == 1) ? at.y : ((j_o == 2) ? at.z : at.w));

    if (upd) {
      const float cs = (float)ci * CONN_K;                 // G*JN*conn
      float I_E = fmaxf(0.382f + 0.21f*E + cs - Ji*I, 0.f);
      float I_I = fmaxf(0.2674f + 0.15f*E - I, 0.f);
      const float xE  = 310.f*I_E - 125.f;
      const float R_E = xE * frcp(1.f - fexp2(-0.23083120f*xE) + 1e-8f);
      const float xI  = 615.f*I_I - 177.f;
      const float R_I = xI * frcp(1.f - fexp2(-0.12551447f*xI) + 1e-8f);
      const float dE = -E*0.01f + (1.f - E)*0.000641f*R_E;
      const float dI = -I*0.1f  + 0.001f*R_I;
      E = fmaxf(E + 0.1f*dE + 0.00158113883f*n0E, 0.f);
      I = fmaxf(I + 0.1f*dI + 0.00158113883f*n0I, 0.f);
      int qv = (int)(E * S_E + 0.5f);
      qv = qv > 127 ? 127 : qv;
      *pbn = (char)qv;
      if (hemo) {
        const float l2v  = flog2(vv);
        const float v_ia = fexp2(3.125f * l2v);            // v**(1/0.32)
        const float v_r  = fexp2(2.125f * l2v);            // v**(1/0.32-1)
        const float ds_  = E - 1.53846153846f*ss - 2.43902439024f*(ff - 1.f);
        const float df_  = ss;
        const float dv_  = (ff - v_ia) * 1.02040816327f;
        const float pw   = fexp2(-0.59946207f * frcp(ff)); // (1-RHO)**(1/f)
        const float dq_  = (ff*2.94117647059f*(1.f - pw) - qq*v_r) * 1.02040816327f;
        ss += 1e-3f*ds_;
        ff += 1e-3f*df_;
        vv += 1e-3f*dv_;
        qq += 1e-3f*dq_;
      }
    }
    n0E = n1E; n0I = n1I;
    n1E = n2E; n1I = n2I;
    lds_barrier();   // next buffer complete; vmcnt loads stay in flight
  };

  for (int hs = 0; hs < NHEMO; ++hs) {
    body(xb0, pb1, true, false);
    body(xb1, pb0, true, false);
    body(xb0, pb1, true, false);
    body(xb1, pb0, true, false);
    body(xb0, pb1, true, false);
    body(xb1, pb0, true, false);
    body(xb0, pb1, true, false);
    body(xb1, pb0, true, false);
    if (hs != NHEMO - 1) {
      body(xb0, pb1, true, false);
      body(xb1, pb0, true, true);
    } else {
      body(xb0, pb1, false, false);
      body(xb1, pb0, false, true);
    }
  }

  // ---- outputs: next_state (N,6,B) then bold (N,B) ----
  if (upd) {
    float* o = out + (size_t)R_o * 6 * NB + b;
    o[0]    = E;
    o[NB]   = I;
    o[2*NB] = ss;
    o[3*NB] = ff;
    o[4*NB] = vv;
    o[5*NB] = qq;
    out[NN*6*NB + R_o*NB + b] =
        20.f*(2.38f*(1.f - qq) + 2.f*(1.f - qq/vv) + 0.48f*(1.f - vv))
        + noise_out[R_o*NB + b];
  }
}

extern "C" void kernel_launch(void* const* d_in, const int* in_sizes, int n_in,
                              void* d_out, int out_size, void* d_ws, size_t ws_size,
                              hipStream_t stream) {
  const float* state     = (const float*)d_in[0];
  // d_in[1] = delays (unused by the reference simulation)
  const float* noise_in  = (const float*)d_in[2];
  const float* noise_out = (const float*)d_in[3];
  const float* sc        = (const float*)d_in[4];
  float* out = (float*)d_out;
  dmf_kernel<<<NB, 512, 0, stream>>>(state, noise_in, noise_out, sc, out);
}